// Round 12
// baseline (976.934 us; speedup 1.0000x reference)
//
#include <hip/hip_runtime.h>
#include <stdint.h>

// L=512, B=32, D=H=256
// Workspace (float offsets into 64MB d_ws):
//   Eq  f16[16384*256] @ 0
//   Ev  f16[16384*256] @ 2097152
//   C   f16[16384*256] @ 4194304
//   Gi2 f16[16384*768] @ 6291456

#define C2    2.8853900817779268f   // 2*log2(e)
#define LOG2E 1.4426950408889634f

typedef __fp16 f16x2 __attribute__((ext_vector_type(2)));
typedef __fp16 f16x8 __attribute__((ext_vector_type(8)));
typedef float f32x4 __attribute__((ext_vector_type(4)));

static __device__ __forceinline__ float rcp_f(float x)  { return __builtin_amdgcn_rcpf(x); }
static __device__ __forceinline__ float exp2_f(float x) { return __builtin_amdgcn_exp2f(x); }
#if __has_builtin(__builtin_amdgcn_rcph)
static __device__ __forceinline__ __fp16 rcph(__fp16 x) {
  return (__fp16)__builtin_amdgcn_rcph((_Float16)x);
}
#else
static __device__ __forceinline__ __fp16 rcph(__fp16 x) {
  return (__fp16)__builtin_amdgcn_rcpf((float)x);
}
#endif
static __device__ __forceinline__ float dot2f(f16x2 a, f16x2 b, float c) {
  return __builtin_amdgcn_fdot2(a, b, c, false);
}
static __device__ __forceinline__ f16x8 cvt8(float4 a, float4 b) {
  f16x8 f;
  f[0] = (__fp16)a.x; f[1] = (__fp16)a.y; f[2] = (__fp16)a.z; f[3] = (__fp16)a.w;
  f[4] = (__fp16)b.x; f[5] = (__fp16)b.y; f[6] = (__fp16)b.z; f[7] = (__fp16)b.w;
  return f;
}

// Fragment conventions (verified end-to-end):
//   A-frag: lane(col=lane&15, quad=lane>>4) holds A[m=col][k=quad*8+jj]
//   B-frag: lane holds B[k=quad*8+jj][n=col]
//   C/D:    row(m)=quad*4+reg, col(n)=lane&15

// ---------------------------------------------------------------------------
// Fused projections -> f16 with exponent clamp to f16-normal range.
// ---------------------------------------------------------------------------
__global__ __launch_bounds__(256) void proj_k(
    const float* __restrict__ v, const float* __restrict__ Wp,
    const float* __restrict__ Wp_, __fp16* __restrict__ Eq,
    __fp16* __restrict__ Ev)
{
  __shared__ __align__(16) __fp16 As[64][40];
  __shared__ __align__(16) __fp16 Wqs[64][40];
  __shared__ __align__(16) __fp16 Wvs[64][40];
  const int t = threadIdx.x, wave = t >> 6, lane = t & 63;
  const int quad = lane >> 4, col = lane & 15;
  const int n0 = blockIdx.x * 64, m0 = blockIdx.y * 64;
  const int srow = t >> 2, skq = t & 3;

  f32x4 accq[4], accv[4];
#pragma unroll
  for (int nt = 0; nt < 4; ++nt) {
    accq[nt] = (f32x4){0.f, 0.f, 0.f, 0.f};
    accv[nt] = (f32x4){0.f, 0.f, 0.f, 0.f};
  }

  for (int kc = 0; kc < 8; ++kc) {
    const int k0 = kc * 32;
    {
      const float4* ap = (const float4*)&v[(size_t)(m0 + srow) * 256 + k0 + skq * 8];
      *(f16x8*)&As[srow][skq * 8] = cvt8(ap[0], ap[1]);
      const float4* qp = (const float4*)&Wp[(size_t)(n0 + srow) * 256 + k0 + skq * 8];
      *(f16x8*)&Wqs[srow][skq * 8] = cvt8(qp[0], qp[1]);
      const float4* vp = (const float4*)&Wp_[(size_t)(n0 + srow) * 256 + k0 + skq * 8];
      *(f16x8*)&Wvs[srow][skq * 8] = cvt8(vp[0], vp[1]);
    }
    __syncthreads();
    f16x8 a = *(const f16x8*)&As[wave * 16 + col][quad * 8];
#pragma unroll
    for (int nt = 0; nt < 4; ++nt) {
      f16x8 bq = *(const f16x8*)&Wqs[nt * 16 + col][quad * 8];
      f16x8 bv = *(const f16x8*)&Wvs[nt * 16 + col][quad * 8];
      accq[nt] = __builtin_amdgcn_mfma_f32_16x16x32_f16(a, bq, accq[nt], 0, 0, 0);
      accv[nt] = __builtin_amdgcn_mfma_f32_16x16x32_f16(a, bv, accv[nt], 0, 0, 0);
    }
    __syncthreads();
  }

#pragma unroll
  for (int nt = 0; nt < 4; ++nt)
#pragma unroll
    for (int r = 0; r < 4; ++r) {
      size_t m = m0 + wave * 16 + quad * 4 + r;
      size_t n = n0 + nt * 16 + col;
      float eq = C2 * accq[nt][r], ev = C2 * accv[nt][r];
      eq = fminf(fmaxf(eq, -14.f), 15.5f);
      ev = fminf(fmaxf(ev, -14.f), 15.5f);
      Eq[m * 256 + n] = (__fp16)exp2_f(eq);
      Ev[m * 256 + n] = (__fp16)exp2_f(ev);
    }
}

// ---------------------------------------------------------------------------
// FUSED attention: scores (packed f16 rcp) -> softmax (regs+shfl) -> context
// (MFMA). Block = (64-row i-tile, batch b): grid (8, 32) x 512 threads.
// Scores S[i][l] held in acc[16][4] regs (thread (tx=l&31, ty-group) owns
// rows ty*4+r, cols lt*32+tx). S never touches global memory.
// LDS phases: {Eqs 64x72 + Evs 512x72} -> {Af 64x520 + Vs 256x40} = 87KB.
// ---------------------------------------------------------------------------
__global__ __launch_bounds__(512, 1) void attn_k(
    const __fp16* __restrict__ Eq, const __fp16* __restrict__ Ev,
    const float* __restrict__ Vvec, const float* __restrict__ v,
    __fp16* __restrict__ C)
{
  __shared__ __align__(16) __fp16 smem[43520];
  __shared__ __align__(16) __fp16 Vsh[256];
  const int t = threadIdx.x;
  const int tx = t & 31, ty = t >> 5;
  const int wave = t >> 6, lane = t & 63;
  const int quad = lane >> 4, col = lane & 15;
  const int i0 = blockIdx.x * 64, b = blockIdx.y;

  if (t < 256) Vsh[t] = (__fp16)(-2.0f * Vvec[b * 256 + t]);

  float acc[16][4];
#pragma unroll
  for (int lt = 0; lt < 16; ++lt)
#pragma unroll
    for (int r = 0; r < 4; ++r) acc[lt][r] = 0.f;

  __fp16* Eqs = smem;          // [64][72]
  __fp16* Evs = smem + 4608;   // [512][72]
  const f16x2 one2 = {(__fp16)1.f, (__fp16)1.f};

  for (int st = 0; st < 4; ++st) {
    const int h0 = st * 64;
    {
      int row = t >> 3, cq = t & 7;
      *(f16x8*)&Eqs[row * 72 + cq * 8] =
          *(const f16x8*)&Eq[((size_t)(i0 + row) * 32 + b) * 256 + h0 + cq * 8];
    }
#pragma unroll
    for (int s = 0; s < 8; ++s) {
      int f = t + s * 512;
      int row = f >> 3, cq = f & 7;
      *(f16x8*)&Evs[row * 72 + cq * 8] =
          *(const f16x8*)&Ev[((size_t)row * 32 + b) * 256 + h0 + cq * 8];
    }
    __syncthreads();

#pragma unroll
    for (int lt = 0; lt < 16; ++lt) {
#pragma unroll
      for (int k8 = 0; k8 < 8; ++k8) {
        f16x8 vh8 = *(const f16x8*)&Vsh[h0 + k8 * 8];
        f16x8 ev8 = *(const f16x8*)&Evs[(lt * 32 + tx) * 72 + k8 * 8];
        f16x8 eq8[4];
#pragma unroll
        for (int r = 0; r < 4; ++r)
          eq8[r] = *(const f16x8*)&Eqs[(ty * 4 + r) * 72 + k8 * 8];
#pragma unroll
        for (int q = 0; q < 4; ++q) {
          f16x2 vh2 = {vh8[q * 2], vh8[q * 2 + 1]};
          f16x2 e2  = {ev8[q * 2], ev8[q * 2 + 1]};
#pragma unroll
          for (int r = 0; r < 4; ++r) {
            f16x2 eq2 = {eq8[r][q * 2], eq8[r][q * 2 + 1]};
            f16x2 d = eq2 * e2 + one2;          // v_pk_fma_f16
            f16x2 rr = {rcph(d[0]), rcph(d[1])};
            acc[lt][r] = dot2f(vh2, rr, acc[lt][r]);
          }
        }
      }
    }
    __syncthreads();
  }

  // softmax over l=512 per row (rows owned by the 32-lane tx-group)
#pragma unroll
  for (int r = 0; r < 4; ++r) {
    float m = -1e30f;
#pragma unroll
    for (int lt = 0; lt < 16; ++lt) m = fmaxf(m, acc[lt][r]);
#pragma unroll
    for (int o = 1; o < 32; o <<= 1) m = fmaxf(m, __shfl_xor(m, o, 64));
    float s = 0.f;
#pragma unroll
    for (int lt = 0; lt < 16; ++lt) {
      acc[lt][r] = exp2_f(LOG2E * (acc[lt][r] - m));
      s += acc[lt][r];
    }
#pragma unroll
    for (int o = 1; o < 32; o <<= 1) s += __shfl_xor(s, o, 64);
    float inv = rcp_f(s);
#pragma unroll
    for (int lt = 0; lt < 16; ++lt) acc[lt][r] *= inv;
  }

  // write A (f16) into LDS, reusing the staging region (all reads complete)
  __fp16* Af = smem;           // [64][520]
#pragma unroll
  for (int r = 0; r < 4; ++r)
#pragma unroll
    for (int lt = 0; lt < 16; ++lt)
      Af[(ty * 4 + r) * 520 + lt * 32 + tx] = (__fp16)acc[lt][r];
  __syncthreads();

  // context: C_tile[64 i][256 d] = A[64][512] @ v_b[512 l][256 d]  (MFMA)
  __fp16* Vs = smem + 33280;   // [256][40]
  const int mt = wave & 3, nh = wave >> 2;
  const int vl = t >> 4, vdq = t & 15;
  f32x4 acc2[8];
#pragma unroll
  for (int n = 0; n < 8; ++n) acc2[n] = (f32x4){0.f, 0.f, 0.f, 0.f};

  for (int kc = 0; kc < 16; ++kc) {
    const int l0 = kc * 32;
    {
      const float4* vp =
          (const float4*)&v[((size_t)(l0 + vl) * 32 + b) * 256 + vdq * 16];
#pragma unroll
      for (int e4 = 0; e4 < 4; ++e4) {
        float4 w = vp[e4];
        Vs[(vdq * 16 + e4 * 4 + 0) * 40 + vl] = (__fp16)w.x;
        Vs[(vdq * 16 + e4 * 4 + 1) * 40 + vl] = (__fp16)w.y;
        Vs[(vdq * 16 + e4 * 4 + 2) * 40 + vl] = (__fp16)w.z;
        Vs[(vdq * 16 + e4 * 4 + 3) * 40 + vl] = (__fp16)w.w;
      }
    }
    __syncthreads();
    f16x8 af = *(const f16x8*)&Af[(mt * 16 + col) * 520 + l0 + quad * 8];
#pragma unroll
    for (int n = 0; n < 8; ++n) {
      f16x8 vf = *(const f16x8*)&Vs[((nh * 8 + n) * 16 + col) * 40 + quad * 8];
      acc2[n] = __builtin_amdgcn_mfma_f32_16x16x32_f16(af, vf, acc2[n], 0, 0, 0);
    }
    __syncthreads();
  }

#pragma unroll
  for (int n = 0; n < 8; ++n)
#pragma unroll
    for (int r = 0; r < 4; ++r) {
      size_t i = i0 + mt * 16 + quad * 4 + r;
      size_t d = (nh * 8 + n) * 16 + col;
      C[(i * 32 + b) * 256 + d] = (__fp16)acc2[n][r];
    }
}

// ---------------------------------------------------------------------------
// Gi2 = f16( C(f16) @ Wih^T + bih (+bhh for gates r,z) ). M=16384,N=768,K=256.
// ---------------------------------------------------------------------------
__global__ __launch_bounds__(256) void gi_k(
    const __fp16* __restrict__ A, const float* __restrict__ W,
    const float* __restrict__ bih, const float* __restrict__ bhh,
    __fp16* __restrict__ G)
{
  __shared__ __align__(16) __fp16 As[64][40];
  __shared__ __align__(16) __fp16 Ws[64][40];
  const int t = threadIdx.x, wave = t >> 6, lane = t & 63;
  const int quad = lane >> 4, col = lane & 15;
  const int n0 = blockIdx.x * 64, m0 = blockIdx.y * 64;
  const int srow = t >> 2, skq = t & 3;

  f32x4 acc[4];
#pragma unroll
  for (int nt = 0; nt < 4; ++nt) acc[nt] = (f32x4){0.f, 0.f, 0.f, 0.f};

  for (int kc = 0; kc < 8; ++kc) {
    const int k0 = kc * 32;
    {
      *(f16x8*)&As[srow][skq * 8] =
          *(const f16x8*)&A[(size_t)(m0 + srow) * 256 + k0 + skq * 8];
      const float4* wp = (const float4*)&W[(size_t)(n0 + srow) * 256 + k0 + skq * 8];
      *(f16x8*)&Ws[srow][skq * 8] = cvt8(wp[0], wp[1]);
    }
    __syncthreads();
    f16x8 a = *(const f16x8*)&As[wave * 16 + col][quad * 8];
#pragma unroll
    for (int nt = 0; nt < 4; ++nt) {
      f16x8 b = *(const f16x8*)&Ws[nt * 16 + col][quad * 8];
      acc[nt] = __builtin_amdgcn_mfma_f32_16x16x32_f16(a, b, acc[nt], 0, 0, 0);
    }
    __syncthreads();
  }

#pragma unroll
  for (int nt = 0; nt < 4; ++nt) {
    int n = n0 + nt * 16 + col;
    float bias = bih[n] + (n < 512 ? bhh[n] : 0.f);
#pragma unroll
    for (int r = 0; r < 4; ++r) {
      size_t m = m0 + wave * 16 + quad * 4 + r;
      G[m * 768 + n] = (__fp16)(acc[nt][r] + bias);
    }
  }
}

// ---------------------------------------------------------------------------
// MFMA GRU, one batch per block (32 blocks x 512 threads). Unchanged from R8.
// ---------------------------------------------------------------------------
__global__ __launch_bounds__(512, 1) void gru_k(
    const __fp16* __restrict__ Gi2, const float* __restrict__ Whh,
    const float* __restrict__ bhh, const float* __restrict__ h0,
    float* __restrict__ out)
{
  __shared__ __align__(16) __fp16 hA[2][256];
  const int t = threadIdx.x, wave = t >> 6, lane = t & 63;
  const int quad = lane >> 4, col = lane & 15;
  const int b = blockIdx.x;
  const int jw = wave * 32;

  f16x8 Bf[2][3][8];
#pragma unroll
  for (int p = 0; p < 2; ++p)
#pragma unroll
    for (int g = 0; g < 3; ++g) {
      const float* wrow = &Whh[(size_t)(g * 256 + jw + p * 16 + col) * 256];
#pragma unroll
      for (int kk = 0; kk < 8; ++kk) {
        const float4* wp = (const float4*)&wrow[kk * 32 + quad * 8];
        Bf[p][g][kk] = cvt8(wp[0], wp[1]);
      }
    }

  float hold[2];
  float bn[2];
#pragma unroll
  for (int p = 0; p < 2; ++p) {
    int j = jw + p * 16 + col;
    bn[p] = bhh[512 + j];
    float h = h0[(size_t)b * 256 + j];
    hold[p] = h;
    if (quad == 0) hA[0][j] = (__fp16)h;
  }
  __syncthreads();

  __fp16 gcur[2][3];
#pragma unroll
  for (int p = 0; p < 2; ++p)
#pragma unroll
    for (int g = 0; g < 3; ++g)
      gcur[p][g] = Gi2[(size_t)b * 768 + g * 256 + jw + p * 16 + col];

  for (int i = 0; i < 512; ++i) {
    __fp16 gnext[2][3];
    {
      int ip = (i + 1 < 512) ? (i + 1) : 511;
#pragma unroll
      for (int p = 0; p < 2; ++p)
#pragma unroll
        for (int g = 0; g < 3; ++g)
          gnext[p][g] =
              Gi2[(size_t)(ip * 32 + b) * 768 + g * 256 + jw + p * 16 + col];
    }

    f32x4 acc[2][3];
#pragma unroll
    for (int p = 0; p < 2; ++p)
#pragma unroll
      for (int g = 0; g < 3; ++g)
        acc[p][g] = (f32x4){0.f, 0.f, 0.f, 0.f};

    const __fp16* hbuf = hA[i & 1];
#pragma unroll
    for (int kk = 0; kk < 8; ++kk) {
      f16x8 a = *(const f16x8*)&hbuf[kk * 32 + quad * 8];
#pragma unroll
      for (int p = 0; p < 2; ++p)
#pragma unroll
        for (int g = 0; g < 3; ++g)
          acc[p][g] = __builtin_amdgcn_mfma_f32_16x16x32_f16(
              a, Bf[p][g][kk], acc[p][g], 0, 0, 0);
    }

    __fp16* hnext = hA[(i + 1) & 1];
#pragma unroll
    for (int p = 0; p < 2; ++p) {
      int j = jw + p * 16 + col;
      float rr = rcp_f(1.f + exp2_f(-LOG2E * ((float)gcur[p][0] + acc[p][0][0])));
      float zz = rcp_f(1.f + exp2_f(-LOG2E * ((float)gcur[p][1] + acc[p][1][0])));
      float na = fmaf(rr, acc[p][2][0] + bn[p], (float)gcur[p][2]);
      float nn = fmaf(-2.f, rcp_f(1.f + exp2_f(C2 * na)), 1.f);
      float h = fmaf(zz, hold[p] - nn, nn);
      hold[p] = h;
      if (quad == 0) {
        out[((size_t)i * 32 + b) * 256 + j] = h;
        hnext[j] = (__fp16)h;
      }
    }
#pragma unroll
    for (int p = 0; p < 2; ++p)
#pragma unroll
      for (int g = 0; g < 3; ++g) gcur[p][g] = gnext[p][g];
    __syncthreads();
  }
}

// ---------------------------------------------------------------------------
extern "C" void kernel_launch(void* const* d_in, const int* in_sizes, int n_in,
                              void* d_out, int out_size, void* d_ws, size_t ws_size,
                              hipStream_t stream)
{
  const float* v   = (const float*)d_in[0];
  const float* h0  = (const float*)d_in[1];
  const float* Vv  = (const float*)d_in[2];
  const float* Wp  = (const float*)d_in[3];
  const float* Wp_ = (const float*)d_in[4];
  const float* Wih = (const float*)d_in[5];
  const float* Whh = (const float*)d_in[6];
  const float* bih = (const float*)d_in[7];
  const float* bhh = (const float*)d_in[8];
  float* out = (float*)d_out;
  float* ws  = (float*)d_ws;

  __fp16* Eq  = (__fp16*)ws;
  __fp16* Ev  = (__fp16*)(ws + 2097152);
  __fp16* C   = (__fp16*)(ws + 4194304);
  __fp16* Gi2 = (__fp16*)(ws + 6291456);

  proj_k<<<dim3(4, 256), 256, 0, stream>>>(v, Wp, Wp_, Eq, Ev);
  attn_k<<<dim3(8, 32), 512, 0, stream>>>(Eq, Ev, Vv, v, C);
  gi_k<<<dim3(12, 256), 256, 0, stream>>>(C, Wih, bih, bhh, Gi2);
  gru_k<<<32, 512, 0, stream>>>(Gi2, Whh, bhh, h0, out);
}